// Round 13
// baseline (62.625 us; speedup 1.0000x reference)
//
#include <hip/hip_runtime.h>

#define PI_F 3.14159265358979323846f

// Problem constants: B=4, Cin=Cout=64, H=W=128, Wf=65, K=3
#define HH 128
#define WW 128
#define WF 65
#define NB 4
#define NC 64
#define CPLX_PER_IMG (HH * WF)                  // 8320

typedef __attribute__((ext_vector_type(8))) short short8;
typedef __attribute__((ext_vector_type(4))) float f32x4;

__device__ __forceinline__ ushort f2b(float f) {   // f32 -> bf16 RNE
    unsigned u = __float_as_uint(f);
    u += 0x7fffu + ((u >> 16) & 1u);
    return (ushort)(u >> 16);
}

// ===================== ws layout (bytes) =====================
// A1: [160][128] @ 0 (40960) | A2: [256][256] @ 40960 | A4: [256][256] @ 172032
// A5: [128][160] @ 303104    | WvRe/WvIm @ 344064/1941504 (2x 1597440)
// XsRe/XsIm @ 12058624/16318464 (2x 4259840) | Zre/Zim @ 20578304/24838144

// ---------------- k_pre: DFT matrices + Wv planes (R8-identical) ----------------
__global__ __launch_bounds__(256) void k_pre(const float* __restrict__ w,
                                             ushort* __restrict__ A1,
                                             ushort* __restrict__ A2,
                                             ushort* __restrict__ A4,
                                             ushort* __restrict__ A5,
                                             ushort* __restrict__ WvRe,
                                             ushort* __restrict__ WvIm) {
    int idx = blockIdx.x * 256 + threadIdx.x;
    if (idx < 20480) {                       // A1[m][k]: m=part*80+v
        int m = idx >> 7, k = idx & 127;
        int part = m / 80, v = m - part * 80;
        float s, c;
        __sincosf(2.f * PI_F * (float)((v * k) & 127) / 128.f, &s, &c);
        float val = (v < 65) ? (part ? -s : c) : 0.f;
        A1[idx] = f2b(val);
    } else if (idx < 86016) {                // A2[m][k2]: fwd col DFT
        int j = idx - 20480;
        int m = j >> 8, k2 = j & 255;
        int part = m >> 7, u = m & 127;
        int kp = k2 >> 7, h = k2 & 127;
        float s, c;
        __sincosf(2.f * PI_F * (float)((u * h) & 127) / 128.f, &s, &c);
        float val = part == 0 ? (kp == 0 ? c : s) : (kp == 0 ? -s : c);
        A2[j] = f2b(val);
    } else if (idx < 151552) {               // A4[m][k2]: inv col DFT, /128
        int j = idx - 86016;
        int m = j >> 8, k2 = j & 255;
        int part = m >> 7, h = m & 127;
        int kp = k2 >> 7, u = k2 & 127;
        float s, c;
        __sincosf(2.f * PI_F * (float)((u * h) & 127) / 128.f, &s, &c);
        float val = part == 0 ? (kp == 0 ? c : -s) : (kp == 0 ? s : c);
        A4[j] = f2b(val * (1.f / 128.f));
    } else if (idx < 172032) {               // A5[x][k2]: c2r, /128
        int j = idx - 151552;
        int x = j / 160, k2 = j - x * 160;
        int part = k2 / 80, v = k2 - part * 80;
        float s, c;
        __sincosf(2.f * PI_F * (float)((v * x) & 127) / 128.f, &s, &c);
        float cv = (v == 0 || v == 64) ? 1.f : 2.f;
        float val = (v < 65) ? (part == 0 ? cv * c : -cv * s) * (1.f / 128.f) : 0.f;
        A5[j] = f2b(val);
    } else {                                 // Wv[p][v][o][i]
        int xw = idx - 172032;               // 0..798719
        int i = xw & 63;
        int o = (xw >> 6) & 63;
        int pv = xw >> 12;
        int p = pv / WF;
        int v = pv % WF;
        const float* wp = w + ((size_t)o * 64 + i) * 9 + p * 3;
        float re = wp[0], im = 0.f;
#pragma unroll
        for (int q = 1; q <= 2; ++q) {
            int k = (v * q) & 127;
            float s, c;
            __sincosf(-2.f * PI_F * (float)k / 128.f, &s, &c);
            re += wp[q] * c;
            im += wp[q] * s;
        }
        WvRe[xw] = f2b(re);
        WvIm[xw] = f2b(im);
    }
}

// ---------------- k_fwd: twin blocks per image. grid 512, 512 threads (8 waves) ---------
// img = bid&255, half = bid>>8 (twins bid/bid+256 land on same CU -> shared L2 for x).
// Both twins: full stage + full S1 (cheap). Split: S2 n-tiles [half*8, half*8+8).
#define B1P 136
#define B2P 280
__global__ __launch_bounds__(512) void k_fwd(const float* __restrict__ x,
                                             const ushort* __restrict__ A1,
                                             const ushort* __restrict__ A2,
                                             ushort* __restrict__ XsRe,
                                             ushort* __restrict__ XsIm) {
    __shared__ ushort B1[128 * B1P];         // 34.8 KB
    __shared__ ushort B2[80 * B2P];          // 44.8 KB  (total 79.6 -> 2 blocks/CU)
    int t = threadIdx.x;
    int img = blockIdx.x & 255;
    int half = blockIdx.x >> 8;
    const float* gx = x + (size_t)img * 16384;
    for (int c = t; c < 2048; c += 512) {    // stage x -> bf16 [h][x]
        int r = c >> 4, sl = c & 15;
        const float* src = gx + r * 128 + sl * 8;
        float4 f0 = *(const float4*)src;
        float4 f1 = *(const float4*)(src + 4);
        short8 v8;
        v8[0] = (short)f2b(f0.x); v8[1] = (short)f2b(f0.y);
        v8[2] = (short)f2b(f0.z); v8[3] = (short)f2b(f0.w);
        v8[4] = (short)f2b(f1.x); v8[5] = (short)f2b(f1.y);
        v8[6] = (short)f2b(f1.z); v8[7] = (short)f2b(f1.w);
        *(short8*)&B1[r * B1P + sl * 8] = v8;
    }
    __syncthreads();
    int lane = t & 63, wave = t >> 6;        // wave 0..7
    int lrow = lane & 15, lq = lane >> 4;

    // ---- S1 (full, duplicated in twins): wave = h-tile, loops all 10 m-tiles ----
    {
        int hrow = wave * 16 + lrow;
        f32x4 acc[10];
#pragma unroll
        for (int j = 0; j < 10; ++j) acc[j] = (f32x4){0.f, 0.f, 0.f, 0.f};
#pragma unroll
        for (int ks = 0; ks < 4; ++ks) {
            short8 b = *(short8*)&B1[hrow * B1P + ks * 32 + lq * 8];
#pragma unroll
            for (int j = 0; j < 10; ++j) {
                short8 a = *(const short8*)&A1[(j * 16 + lrow) * 128 + ks * 32 + lq * 8];
                acc[j] = __builtin_amdgcn_mfma_f32_16x16x32_bf16(a, b, acc[j], 0, 0, 0);
            }
        }
#pragma unroll
        for (int j = 0; j < 10; ++j) {
            int m0 = j * 16 + lq * 4;
            int part = m0 >= 80;
            int v0 = m0 - part * 80;
#pragma unroll
            for (int e = 0; e < 4; ++e)
                B2[(v0 + e) * B2P + part * 128 + hrow] = f2b(acc[j][e]);
        }
    }
    __syncthreads();

    // ---- S2 (split): wave owns n-tile = half*8 + wave ----
    {
        int nt = half * 8 + wave;
        f32x4 acc[5];
#pragma unroll
        for (int mt = 0; mt < 5; ++mt) acc[mt] = (f32x4){0.f, 0.f, 0.f, 0.f};
#pragma unroll
        for (int ks = 0; ks < 8; ++ks) {
            short8 b = *(const short8*)&A2[(nt * 16 + lrow) * 256 + ks * 32 + lq * 8];
#pragma unroll
            for (int mt = 0; mt < 5; ++mt) {
                short8 a = *(short8*)&B2[(mt * 16 + lrow) * B2P + ks * 32 + lq * 8];
                acc[mt] = __builtin_amdgcn_mfma_f32_16x16x32_bf16(a, b, acc[mt], 0, 0, 0);
            }
        }
        int part = nt >= 8;
        int u = (nt & 7) * 16 + lrow;
        int u_out = (u + 64) & 127;
        int du = u_out - 64;
        ushort* dimg = (part ? XsIm : XsRe) + (size_t)img * CPLX_PER_IMG;
#pragma unroll
        for (int mt = 0; mt < 5; ++mt)
#pragma unroll
            for (int e = 0; e < 4; ++e) {
                int v_in = mt * 16 + lq * 4 + e;
                if (v_in < 65) {
                    int v_out = v_in + 32; if (v_out >= 65) v_out -= 65;
                    int dv = v_out - 64;
                    bool keep = (du * du + dv * dv) > 900;
                    dimg[v_out * 128 + u_out] = keep ? f2b(acc[mt][e]) : (ushort)0;
                }
            }
    }
}

// ---------------- k_gemm: per-(v,b) complex GEMM via bf16 MFMA + phase fold (R8) --------
#define AP 72
__global__ __launch_bounds__(256, 2) void k_gemm(const ushort* __restrict__ XsRe,
                                                 const ushort* __restrict__ XsIm,
                                                 const ushort* __restrict__ WvRe,
                                                 const ushort* __restrict__ WvIm,
                                                 ushort* __restrict__ Zre,
                                                 ushort* __restrict__ Zim) {
    __shared__ ushort XTre[128 * AP], XTim[128 * AP];
    __shared__ ushort WSre[64 * AP],  WSim[64 * AP];
    int t = threadIdx.x;
    int v = blockIdx.x >> 2;
    int b = blockIdx.x & 3;
    {
        int u = t & 127, qh = t >> 7;
#pragma unroll
        for (int q8 = 0; q8 < 8; ++q8) {
            int q = qh * 8 + q8;
            ushort re4[4], im4[4];
#pragma unroll
            for (int c = 0; c < 4; ++c) {
                int i = q * 4 + c;
                size_t off = ((size_t)(b * 64 + i) * WF + v) * 128 + u;
                re4[c] = XsRe[off];
                im4[c] = XsIm[off];
            }
            *(ushort4*)&XTre[u * AP + q * 4] = make_ushort4(re4[0], re4[1], re4[2], re4[3]);
            *(ushort4*)&XTim[u * AP + q * 4] = make_ushort4(im4[0], im4[1], im4[2], im4[3]);
        }
    }
    int lane = t & 63, wave = t >> 6;
    int lrow = lane & 15, lq = lane >> 4;
    int u0 = wave * 32;
    f32x4 fRe[8], fIm[8];
#pragma unroll
    for (int m = 0; m < 8; ++m) {
        fRe[m] = (f32x4){0.f, 0.f, 0.f, 0.f};
        fIm[m] = (f32x4){0.f, 0.f, 0.f, 0.f};
    }
    for (int p = 0; p < 3; ++p) {
        if (p) __syncthreads();
        {
            const ushort* gr = WvRe + ((size_t)(p * WF + v)) * 4096;
            const ushort* gi = WvIm + ((size_t)(p * WF + v)) * 4096;
#pragma unroll
            for (int cc = 0; cc < 2; ++cc) {
                int c = t + cc * 256;
                int o = c >> 3, i0 = (c & 7) * 8;
                *(short8*)&WSre[o * AP + i0] = *(const short8*)&gr[c * 8];
                *(short8*)&WSim[o * AP + i0] = *(const short8*)&gi[c * 8];
            }
        }
        __syncthreads();
        f32x4 pRe[8], pIm[8];
#pragma unroll
        for (int m = 0; m < 8; ++m) {
            pRe[m] = (f32x4){0.f, 0.f, 0.f, 0.f};
            pIm[m] = (f32x4){0.f, 0.f, 0.f, 0.f};
        }
#pragma unroll
        for (int ks = 0; ks < 2; ++ks) {
            int kb = ks * 32 + lq * 8;
            short8 br[2], bi[2], bin[2];
#pragma unroll
            for (int ut = 0; ut < 2; ++ut) {
                int u = u0 + ut * 16 + lrow;
                br[ut] = *(const short8*)&XTre[u * AP + kb];
                bi[ut] = *(const short8*)&XTim[u * AP + kb];
                bin[ut] = bi[ut] ^ (short)0x8000;
            }
#pragma unroll
            for (int ot = 0; ot < 4; ++ot) {
                int o = ot * 16 + lrow;
                short8 ar = *(const short8*)&WSre[o * AP + kb];
                short8 ai = *(const short8*)&WSim[o * AP + kb];
#pragma unroll
                for (int ut = 0; ut < 2; ++ut) {
                    int m = ot * 2 + ut;
                    pRe[m] = __builtin_amdgcn_mfma_f32_16x16x32_bf16(ai, bin[ut], pRe[m], 0, 0, 0);
                    pRe[m] = __builtin_amdgcn_mfma_f32_16x16x32_bf16(ar, br[ut],  pRe[m], 0, 0, 0);
                    pIm[m] = __builtin_amdgcn_mfma_f32_16x16x32_bf16(ai, br[ut],  pIm[m], 0, 0, 0);
                    pIm[m] = __builtin_amdgcn_mfma_f32_16x16x32_bf16(ar, bi[ut],  pIm[m], 0, 0, 0);
                }
            }
        }
#pragma unroll
        for (int ut = 0; ut < 2; ++ut) {
            int u = u0 + ut * 16 + lrow;
            float sn, cn;
            __sincosf(-2.f * PI_F * (float)(u * p) / 128.f, &sn, &cn);
#pragma unroll
            for (int ot = 0; ot < 4; ++ot) {
                int m = ot * 2 + ut;
#pragma unroll
                for (int e = 0; e < 4; ++e) {
                    fRe[m][e] += pRe[m][e] * cn - pIm[m][e] * sn;
                    fIm[m][e] += pIm[m][e] * cn + pRe[m][e] * sn;
                }
            }
        }
    }
#pragma unroll
    for (int ot = 0; ot < 4; ++ot)
#pragma unroll
        for (int ut = 0; ut < 2; ++ut) {
            int m = ot * 2 + ut;
            int u = u0 + ut * 16 + lrow;
#pragma unroll
            for (int e = 0; e < 4; ++e) {
                int o = ot * 16 + lq * 4 + e;
                size_t idx = ((size_t)(b * 64 + o) * WF + v) * 128 + u;
                Zre[idx] = f2b(fRe[m][e]);
                Zim[idx] = f2b(fIm[m][e]);
            }
        }
}

// ---------------- k_inv: twin blocks per channel. grid 512, 512 threads (8 waves) -------
// ch = bid&255, H = bid>>8. Both twins: full Z stage + S4 for their h-half (8 m-tiles).
// Split: S5 h-rows [H*64, H*64+64). B2 local holds only the half: [64][168].
#define B3P 168
__global__ __launch_bounds__(512) void k_inv(const ushort* __restrict__ Zre,
                                             const ushort* __restrict__ Zim,
                                             const ushort* __restrict__ A4,
                                             const ushort* __restrict__ A5,
                                             const float* __restrict__ bias,
                                             float* __restrict__ out) {
    __shared__ ushort B1[80 * B2P];          // 44.8 KB
    __shared__ ushort B2[64 * B3P];          // 21.5 KB  (total 66.3 -> 2 blocks/CU)
    int t = threadIdx.x;
    int ch = blockIdx.x & 255;
    int H = blockIdx.x >> 8;
    for (int c = t; c < 2080; c += 512) {    // stage Z -> [v][kp*128+u]
        int r = c >> 5, sl = c & 31;
        const ushort* src = (sl < 16 ? Zre : Zim) + ((size_t)ch * WF + r) * 128 + (sl & 15) * 8;
        *(short8*)&B1[r * B2P + sl * 8] = *(const short8*)src;
    }
    if (t < 480) {                           // zero pad rows v=65..79
        int r = 65 + (t >> 5), sl = t & 31;
        short8 z = {0, 0, 0, 0, 0, 0, 0, 0};
        *(short8*)&B1[r * B2P + sl * 8] = z;
    }
    __syncthreads();
    int lane = t & 63, wave = t >> 6;        // wave 0..7
    int lrow = lane & 15, lq = lane >> 4;

    // ---- S4 (h-half): wave -> (part = w>>2, j = w&3), mt = part*8 + H*4 + j ----
    {
        int part = wave >> 2, j = wave & 3;
        int mt = part * 8 + H * 4 + j;
        f32x4 acc[5];
#pragma unroll
        for (int nt = 0; nt < 5; ++nt) acc[nt] = (f32x4){0.f, 0.f, 0.f, 0.f};
#pragma unroll
        for (int ks = 0; ks < 8; ++ks) {
            short8 a = *(const short8*)&A4[(mt * 16 + lrow) * 256 + ks * 32 + lq * 8];
#pragma unroll
            for (int nt = 0; nt < 5; ++nt) {
                short8 b = *(short8*)&B1[(nt * 16 + lrow) * B2P + ks * 32 + lq * 8];
                acc[nt] = __builtin_amdgcn_mfma_f32_16x16x32_bf16(a, b, acc[nt], 0, 0, 0);
            }
        }
        int h0l = j * 16 + lq * 4;           // local h row in [0,64)
#pragma unroll
        for (int nt = 0; nt < 5; ++nt) {
            int v = nt * 16 + lrow;
#pragma unroll
            for (int e = 0; e < 4; ++e)
                B2[(h0l + e) * B3P + part * 80 + v] = f2b(acc[nt][e]);
        }
    }
    __syncthreads();

    // ---- S5 (h-half): wave -> (mtl = w&3, nh = w>>2); 4 n-tiles each ----
    {
        int mtl = wave & 3, nh = wave >> 2;
        f32x4 acc[4];
#pragma unroll
        for (int jn = 0; jn < 4; ++jn) acc[jn] = (f32x4){0.f, 0.f, 0.f, 0.f};
#pragma unroll
        for (int ks = 0; ks < 5; ++ks) {
            short8 a = *(short8*)&B2[(mtl * 16 + lrow) * B3P + ks * 32 + lq * 8];
#pragma unroll
            for (int jn = 0; jn < 4; ++jn) {
                int nt = nh * 4 + jn;
                short8 b = *(const short8*)&A5[(nt * 16 + lrow) * 160 + ks * 32 + lq * 8];
                acc[jn] = __builtin_amdgcn_mfma_f32_16x16x32_bf16(a, b, acc[jn], 0, 0, 0);
            }
        }
        float bo = bias[ch & 63];
        float* go = out + (size_t)ch * 16384;
#pragma unroll
        for (int jn = 0; jn < 4; ++jn) {
            int xx = (nh * 4 + jn) * 16 + lrow;
#pragma unroll
            for (int e = 0; e < 4; ++e) {
                int h = H * 64 + mtl * 16 + lq * 4 + e;
                go[h * 128 + xx] = acc[jn][e] + bo;
            }
        }
    }
}

extern "C" void kernel_launch(void* const* d_in, const int* in_sizes, int n_in,
                              void* d_out, int out_size, void* d_ws, size_t ws_size,
                              hipStream_t stream) {
    const float* x = (const float*)d_in[0];      // [4,64,128,128]
    const float* w = (const float*)d_in[1];      // [64,64,3,3]
    const float* bias = (const float*)d_in[2];   // [64]
    float* out = (float*)d_out;                  // [4,64,128,128]

    char* ws = (char*)d_ws;
    ushort* A1   = (ushort*)(ws + 0);
    ushort* A2   = (ushort*)(ws + 40960);
    ushort* A4   = (ushort*)(ws + 172032);
    ushort* A5   = (ushort*)(ws + 303104);
    ushort* WvRe = (ushort*)(ws + 344064);
    ushort* WvIm = (ushort*)(ws + 1941504);
    ushort* XsRe = (ushort*)(ws + 12058624);
    ushort* XsIm = (ushort*)(ws + 16318464);
    ushort* Zre  = (ushort*)(ws + 20578304);
    ushort* Zim  = (ushort*)(ws + 24838144);

    k_pre<<<3792, 256, 0, stream>>>(w, A1, A2, A4, A5, WvRe, WvIm);
    k_fwd<<<512, 512, 0, stream>>>(x, A1, A2, XsRe, XsIm);
    k_gemm<<<WF * NB, 256, 0, stream>>>(XsRe, XsIm, WvRe, WvIm, Zre, Zim);
    k_inv<<<512, 512, 0, stream>>>(Zre, Zim, A4, A5, bias, out);
}

// Round 14
// 47.126 us; speedup vs baseline: 1.3289x; 1.3289x over previous
//
#include <hip/hip_runtime.h>

#define PI_F 3.14159265358979323846f

// Problem constants: B=4, Cin=Cout=64, H=W=128, Wf=65, K=3
#define HH 128
#define WW 128
#define WF 65
#define NB 4
#define NC 64
#define CPLX_PER_IMG (HH * WF)                  // 8320

typedef __attribute__((ext_vector_type(8))) short short8;
typedef __attribute__((ext_vector_type(4))) float f32x4;

__device__ __forceinline__ ushort f2b(float f) {   // f32 -> bf16 RNE
    unsigned u = __float_as_uint(f);
    u += 0x7fffu + ((u >> 16) & 1u);
    return (ushort)(u >> 16);
}

// ===================== ws layout (bytes) =====================
// A4: [256][256] @ 172032 | A5: [128][160] @ 303104
// WvRe/WvIm @ 344064/1941504 (2x 1597440)
// XsRe/XsIm @ 12058624/16318464 (2x 4259840) | Zre/Zim @ 20578304/24838144

// ---------------- graft item: Wv planes + A4 + A5 (idx in [86016, 970752)) -------------
// Byte-identical math to the old k_pre branches.
__device__ __forceinline__ void pre_item_tail(int idx, const float* __restrict__ w,
                                              ushort* __restrict__ A4,
                                              ushort* __restrict__ A5,
                                              ushort* __restrict__ WvRe,
                                              ushort* __restrict__ WvIm) {
    if (idx < 151552) {                      // A4[m][k2]: inv col DFT, /128
        int j = idx - 86016;
        int m = j >> 8, k2 = j & 255;
        int part = m >> 7, h = m & 127;
        int kp = k2 >> 7, u = k2 & 127;
        float s, c;
        __sincosf(2.f * PI_F * (float)((u * h) & 127) / 128.f, &s, &c);
        float val = part == 0 ? (kp == 0 ? c : -s) : (kp == 0 ? s : c);
        A4[j] = f2b(val * (1.f / 128.f));
    } else if (idx < 172032) {               // A5[x][k2]: c2r, /128
        int j = idx - 151552;
        int x = j / 160, k2 = j - x * 160;
        int part = k2 / 80, v = k2 - part * 80;
        float s, c;
        __sincosf(2.f * PI_F * (float)((v * x) & 127) / 128.f, &s, &c);
        float cv = (v == 0 || v == 64) ? 1.f : 2.f;
        float val = (v < 65) ? (part == 0 ? cv * c : -cv * s) * (1.f / 128.f) : 0.f;
        A5[j] = f2b(val);
    } else {                                 // Wv[p][v][o][i]
        int xw = idx - 172032;               // 0..798719
        int i = xw & 63;
        int o = (xw >> 6) & 63;
        int pv = xw >> 12;
        int p = pv / WF;
        int v = pv % WF;
        const float* wp = w + ((size_t)o * 64 + i) * 9 + p * 3;
        float re = wp[0], im = 0.f;
#pragma unroll
        for (int q = 1; q <= 2; ++q) {
            int k = (v * q) & 127;
            float s, c;
            __sincosf(-2.f * PI_F * (float)k / 128.f, &s, &c);
            re += wp[q] * c;
            im += wp[q] * s;
        }
        WvRe[xw] = f2b(re);
        WvIm[xw] = f2b(im);
    }
}

// ---------------- k_fwd: self-sufficient. A1 in LDS, A2 in registers, graft Wv/A4/A5 ----
// grid 256, 1024 threads (16 waves). LDS: B1[128][136] + B2[80][280] + A1L[160][136]
// = 120.2 KiB -> 1 block/CU (same as R8).
#define B1P 136
#define B2P 280
#define A1P 136
__global__ __launch_bounds__(1024) void k_fwd(const float* __restrict__ x,
                                              const float* __restrict__ w,
                                              ushort* __restrict__ XsRe,
                                              ushort* __restrict__ XsIm,
                                              ushort* __restrict__ WvRe,
                                              ushort* __restrict__ WvIm,
                                              ushort* __restrict__ A4,
                                              ushort* __restrict__ A5) {
    __shared__ ushort B1[128 * B1P];         // 34.8 KB
    __shared__ ushort B2[80 * B2P];          // 44.8 KB
    __shared__ ushort A1L[160 * A1P];        // 42.5 KB
    int t = threadIdx.x;
    int img = blockIdx.x;
    const float* gx = x + (size_t)img * 16384;

    // ---- stage x -> bf16 [h][x] (longest-latency loads first) ----
    for (int c = t; c < 2048; c += 1024) {
        int r = c >> 4, sl = c & 15;
        const float* src = gx + r * 128 + sl * 8;
        float4 f0 = *(const float4*)src;
        float4 f1 = *(const float4*)(src + 4);
        short8 v8;
        v8[0] = (short)f2b(f0.x); v8[1] = (short)f2b(f0.y);
        v8[2] = (short)f2b(f0.z); v8[3] = (short)f2b(f0.w);
        v8[4] = (short)f2b(f1.x); v8[5] = (short)f2b(f1.y);
        v8[6] = (short)f2b(f1.z); v8[7] = (short)f2b(f1.w);
        *(short8*)&B1[r * B1P + sl * 8] = v8;
    }
    // ---- generate A1 into LDS: 20480 items, 20/thread ----
    for (int idx = t; idx < 20480; idx += 1024) {
        int m = idx >> 7, k = idx & 127;
        int part = m / 80, v = m - part * 80;
        float s, c;
        __sincosf(2.f * PI_F * (float)((v * k) & 127) / 128.f, &s, &c);
        float val = (v < 65) ? (part ? -s : c) : 0.f;
        A1L[m * A1P + k] = f2b(val);
    }
    // ---- graft: Wv/A4/A5 for the later kernels (uniform ~3.4 items/thread) ----
    {
        int gtid = img * 1024 + t;           // [0, 262144)
        for (int idx = 86016 + gtid; idx < 970752; idx += 262144)
            pre_item_tail(idx, w, A4, A5, WvRe, WvIm);
    }
    __syncthreads();

    int lane = t & 63, wave = t >> 6;        // wave 0..15
    int lrow = lane & 15, lq = lane >> 4;

    // ---- S1: C[m=(part,v)][n=h]; wave (g=w>>3, nt=w&7): 5 m-tiles x 1 h-tile ----
    {
        int g = wave >> 3, nt = wave & 7;
        int hrow = nt * 16 + lrow;
        f32x4 acc[5];
#pragma unroll
        for (int j = 0; j < 5; ++j) acc[j] = (f32x4){0.f, 0.f, 0.f, 0.f};
#pragma unroll
        for (int ks = 0; ks < 4; ++ks) {
            short8 b = *(short8*)&B1[hrow * B1P + ks * 32 + lq * 8];
#pragma unroll
            for (int j = 0; j < 5; ++j) {
                int mt = g * 5 + j;
                short8 a = *(const short8*)&A1L[(mt * 16 + lrow) * A1P + ks * 32 + lq * 8];
                acc[j] = __builtin_amdgcn_mfma_f32_16x16x32_bf16(a, b, acc[j], 0, 0, 0);
            }
        }
#pragma unroll
        for (int j = 0; j < 5; ++j) {
            int m0 = (g * 5 + j) * 16 + lq * 4;
            int part = m0 >= 80;
            int v0 = m0 - part * 80;
#pragma unroll
            for (int e = 0; e < 4; ++e)
                B2[(v0 + e) * B2P + part * 128 + hrow] = f2b(acc[j][e]);
        }
    }
    __syncthreads();

    // ---- S2 (swapped): C[m=v][n=(part,u)]; wave owns n-tile = wave; A2 row in regs ----
    {
        int nt = wave;
        int part = nt >= 8;
        int um = (nt & 7) * 16 + lrow;       // u_m = m&127 of A2 row
        f32x4 acc[5];
#pragma unroll
        for (int mt = 0; mt < 5; ++mt) acc[mt] = (f32x4){0.f, 0.f, 0.f, 0.f};
#pragma unroll
        for (int ks = 0; ks < 8; ++ks) {
            int kp = ks >> 2;
            int hbase = (ks & 3) * 32 + lq * 8;
            short8 bfr;
#pragma unroll
            for (int e = 0; e < 8; ++e) {
                int hh = hbase + e;
                float s, c;
                __sincosf(2.f * PI_F * (float)((um * hh) & 127) / 128.f, &s, &c);
                float val = !part ? (kp == 0 ? c : s) : (kp == 0 ? -s : c);
                bfr[e] = (short)f2b(val);
            }
#pragma unroll
            for (int mt = 0; mt < 5; ++mt) {
                short8 a = *(short8*)&B2[(mt * 16 + lrow) * B2P + ks * 32 + lq * 8];
                acc[mt] = __builtin_amdgcn_mfma_f32_16x16x32_bf16(a, bfr, acc[mt], 0, 0, 0);
            }
        }
        int u = (nt & 7) * 16 + lrow;
        int u_out = (u + 64) & 127;
        int du = u_out - 64;
        ushort* dimg = (part ? XsIm : XsRe) + (size_t)img * CPLX_PER_IMG;
#pragma unroll
        for (int mt = 0; mt < 5; ++mt)
#pragma unroll
            for (int e = 0; e < 4; ++e) {
                int v_in = mt * 16 + lq * 4 + e;
                if (v_in < 65) {
                    int v_out = v_in + 32; if (v_out >= 65) v_out -= 65;
                    int dv = v_out - 64;
                    bool keep = (du * du + dv * dv) > 900;
                    dimg[v_out * 128 + u_out] = keep ? f2b(acc[mt][e]) : (ushort)0;
                }
            }
    }
}

// ---------------- k_gemm: per-(v,b) complex GEMM via bf16 MFMA + phase fold (R8 exact) --
#define AP 72
__global__ __launch_bounds__(256, 2) void k_gemm(const ushort* __restrict__ XsRe,
                                                 const ushort* __restrict__ XsIm,
                                                 const ushort* __restrict__ WvRe,
                                                 const ushort* __restrict__ WvIm,
                                                 ushort* __restrict__ Zre,
                                                 ushort* __restrict__ Zim) {
    __shared__ ushort XTre[128 * AP], XTim[128 * AP];
    __shared__ ushort WSre[64 * AP],  WSim[64 * AP];
    int t = threadIdx.x;
    int v = blockIdx.x >> 2;
    int b = blockIdx.x & 3;
    {
        int u = t & 127, qh = t >> 7;
#pragma unroll
        for (int q8 = 0; q8 < 8; ++q8) {
            int q = qh * 8 + q8;
            ushort re4[4], im4[4];
#pragma unroll
            for (int c = 0; c < 4; ++c) {
                int i = q * 4 + c;
                size_t off = ((size_t)(b * 64 + i) * WF + v) * 128 + u;
                re4[c] = XsRe[off];
                im4[c] = XsIm[off];
            }
            *(ushort4*)&XTre[u * AP + q * 4] = make_ushort4(re4[0], re4[1], re4[2], re4[3]);
            *(ushort4*)&XTim[u * AP + q * 4] = make_ushort4(im4[0], im4[1], im4[2], im4[3]);
        }
    }
    int lane = t & 63, wave = t >> 6;
    int lrow = lane & 15, lq = lane >> 4;
    int u0 = wave * 32;
    f32x4 fRe[8], fIm[8];
#pragma unroll
    for (int m = 0; m < 8; ++m) {
        fRe[m] = (f32x4){0.f, 0.f, 0.f, 0.f};
        fIm[m] = (f32x4){0.f, 0.f, 0.f, 0.f};
    }
    for (int p = 0; p < 3; ++p) {
        if (p) __syncthreads();
        {
            const ushort* gr = WvRe + ((size_t)(p * WF + v)) * 4096;
            const ushort* gi = WvIm + ((size_t)(p * WF + v)) * 4096;
#pragma unroll
            for (int cc = 0; cc < 2; ++cc) {
                int c = t + cc * 256;
                int o = c >> 3, i0 = (c & 7) * 8;
                *(short8*)&WSre[o * AP + i0] = *(const short8*)&gr[c * 8];
                *(short8*)&WSim[o * AP + i0] = *(const short8*)&gi[c * 8];
            }
        }
        __syncthreads();
        f32x4 pRe[8], pIm[8];
#pragma unroll
        for (int m = 0; m < 8; ++m) {
            pRe[m] = (f32x4){0.f, 0.f, 0.f, 0.f};
            pIm[m] = (f32x4){0.f, 0.f, 0.f, 0.f};
        }
#pragma unroll
        for (int ks = 0; ks < 2; ++ks) {
            int kb = ks * 32 + lq * 8;
            short8 br[2], bi[2], bin[2];
#pragma unroll
            for (int ut = 0; ut < 2; ++ut) {
                int u = u0 + ut * 16 + lrow;
                br[ut] = *(const short8*)&XTre[u * AP + kb];
                bi[ut] = *(const short8*)&XTim[u * AP + kb];
                bin[ut] = bi[ut] ^ (short)0x8000;
            }
#pragma unroll
            for (int ot = 0; ot < 4; ++ot) {
                int o = ot * 16 + lrow;
                short8 ar = *(const short8*)&WSre[o * AP + kb];
                short8 ai = *(const short8*)&WSim[o * AP + kb];
#pragma unroll
                for (int ut = 0; ut < 2; ++ut) {
                    int m = ot * 2 + ut;
                    pRe[m] = __builtin_amdgcn_mfma_f32_16x16x32_bf16(ai, bin[ut], pRe[m], 0, 0, 0);
                    pRe[m] = __builtin_amdgcn_mfma_f32_16x16x32_bf16(ar, br[ut],  pRe[m], 0, 0, 0);
                    pIm[m] = __builtin_amdgcn_mfma_f32_16x16x32_bf16(ai, br[ut],  pIm[m], 0, 0, 0);
                    pIm[m] = __builtin_amdgcn_mfma_f32_16x16x32_bf16(ar, bi[ut],  pIm[m], 0, 0, 0);
                }
            }
        }
#pragma unroll
        for (int ut = 0; ut < 2; ++ut) {
            int u = u0 + ut * 16 + lrow;
            float sn, cn;
            __sincosf(-2.f * PI_F * (float)(u * p) / 128.f, &sn, &cn);
#pragma unroll
            for (int ot = 0; ot < 4; ++ot) {
                int m = ot * 2 + ut;
#pragma unroll
                for (int e = 0; e < 4; ++e) {
                    fRe[m][e] += pRe[m][e] * cn - pIm[m][e] * sn;
                    fIm[m][e] += pIm[m][e] * cn + pRe[m][e] * sn;
                }
            }
        }
    }
#pragma unroll
    for (int ot = 0; ot < 4; ++ot)
#pragma unroll
        for (int ut = 0; ut < 2; ++ut) {
            int m = ot * 2 + ut;
            int u = u0 + ut * 16 + lrow;
#pragma unroll
            for (int e = 0; e < 4; ++e) {
                int o = ot * 16 + lq * 4 + e;
                size_t idx = ((size_t)(b * 64 + o) * WF + v) * 128 + u;
                Zre[idx] = f2b(fRe[m][e]);
                Zim[idx] = f2b(fIm[m][e]);
            }
        }
}

// ---------------- k_inv: per-ch S4 + S5 (R8 exact) ----------------
#define B3P 168
__global__ __launch_bounds__(1024) void k_inv(const ushort* __restrict__ Zre,
                                              const ushort* __restrict__ Zim,
                                              const ushort* __restrict__ A4,
                                              const ushort* __restrict__ A5,
                                              const float* __restrict__ bias,
                                              float* __restrict__ out) {
    __shared__ ushort B1[80 * B2P];          // 44.8 KB
    __shared__ ushort B2[128 * B3P];         // 43.0 KB
    int t = threadIdx.x;
    int ch = blockIdx.x;
    for (int c = t; c < 2080; c += 1024) {   // stage Z -> [v][kp*128+u]
        int r = c >> 5, sl = c & 31;
        const ushort* src = (sl < 16 ? Zre : Zim) + ((size_t)ch * WF + r) * 128 + (sl & 15) * 8;
        *(short8*)&B1[r * B2P + sl * 8] = *(const short8*)src;
    }
    if (t < 480) {                           // zero pad rows v=65..79
        int r = 65 + (t >> 5), sl = t & 31;
        short8 z = {0, 0, 0, 0, 0, 0, 0, 0};
        *(short8*)&B1[r * B2P + sl * 8] = z;
    }
    __syncthreads();
    int lane = t & 63, wave = t >> 6;        // wave 0..15
    int lrow = lane & 15, lq = lane >> 4;

    // ---- S4: C[m=(part,h)][n=v]; wave owns m-tile = wave, all 5 n-tiles ----
    {
        int mt = wave;
        f32x4 acc[5];
#pragma unroll
        for (int nt = 0; nt < 5; ++nt) acc[nt] = (f32x4){0.f, 0.f, 0.f, 0.f};
#pragma unroll
        for (int ks = 0; ks < 8; ++ks) {
            short8 a = *(const short8*)&A4[(mt * 16 + lrow) * 256 + ks * 32 + lq * 8];
#pragma unroll
            for (int nt = 0; nt < 5; ++nt) {
                short8 b = *(short8*)&B1[(nt * 16 + lrow) * B2P + ks * 32 + lq * 8];
                acc[nt] = __builtin_amdgcn_mfma_f32_16x16x32_bf16(a, b, acc[nt], 0, 0, 0);
            }
        }
        int part = mt >= 8;
        int h0 = mt * 16 + lq * 4 - part * 128;
#pragma unroll
        for (int nt = 0; nt < 5; ++nt) {
            int v = nt * 16 + lrow;
#pragma unroll
            for (int e = 0; e < 4; ++e)
                B2[(h0 + e) * B3P + part * 80 + v] = f2b(acc[nt][e]);
        }
    }
    __syncthreads();

    // ---- S5 (swapped): C[m=h][n=x]; wave (mt=w&7, nh=w>>3): 4 n-tiles ----
    {
        int mt = wave & 7, nh = wave >> 3;
        f32x4 acc[4];
#pragma unroll
        for (int jn = 0; jn < 4; ++jn) acc[jn] = (f32x4){0.f, 0.f, 0.f, 0.f};
#pragma unroll
        for (int ks = 0; ks < 5; ++ks) {
            short8 a = *(short8*)&B2[(mt * 16 + lrow) * B3P + ks * 32 + lq * 8];
#pragma unroll
            for (int jn = 0; jn < 4; ++jn) {
                int nt = nh * 4 + jn;
                short8 b = *(const short8*)&A5[(nt * 16 + lrow) * 160 + ks * 32 + lq * 8];
                acc[jn] = __builtin_amdgcn_mfma_f32_16x16x32_bf16(a, b, acc[jn], 0, 0, 0);
            }
        }
        float bo = bias[ch & 63];
        float* go = out + (size_t)ch * 16384;
#pragma unroll
        for (int jn = 0; jn < 4; ++jn) {
            int xx = (nh * 4 + jn) * 16 + lrow;
#pragma unroll
            for (int e = 0; e < 4; ++e) {
                int h = mt * 16 + lq * 4 + e;
                go[h * 128 + xx] = acc[jn][e] + bo;
            }
        }
    }
}

extern "C" void kernel_launch(void* const* d_in, const int* in_sizes, int n_in,
                              void* d_out, int out_size, void* d_ws, size_t ws_size,
                              hipStream_t stream) {
    const float* x = (const float*)d_in[0];      // [4,64,128,128]
    const float* w = (const float*)d_in[1];      // [64,64,3,3]
    const float* bias = (const float*)d_in[2];   // [64]
    float* out = (float*)d_out;                  // [4,64,128,128]

    char* ws = (char*)d_ws;
    ushort* A4   = (ushort*)(ws + 172032);
    ushort* A5   = (ushort*)(ws + 303104);
    ushort* WvRe = (ushort*)(ws + 344064);
    ushort* WvIm = (ushort*)(ws + 1941504);
    ushort* XsRe = (ushort*)(ws + 12058624);
    ushort* XsIm = (ushort*)(ws + 16318464);
    ushort* Zre  = (ushort*)(ws + 20578304);
    ushort* Zim  = (ushort*)(ws + 24838144);

    k_fwd<<<NB * NC, 1024, 0, stream>>>(x, w, XsRe, XsIm, WvRe, WvIm, A4, A5);
    k_gemm<<<WF * NB, 256, 0, stream>>>(XsRe, XsIm, WvRe, WvIm, Zre, Zim);
    k_inv<<<NB * NC, 1024, 0, stream>>>(Zre, Zim, A4, A5, bias, out);
}

// Round 15
// 46.959 us; speedup vs baseline: 1.3336x; 1.0036x over previous
//
#include <hip/hip_runtime.h>

#define PI_F 3.14159265358979323846f

// Problem constants: B=4, Cin=Cout=64, H=W=128, Wf=65, K=3
#define HH 128
#define WW 128
#define WF 65
#define NB 4
#define NC 64
#define CPLX_PER_IMG (HH * WF)                  // 8320

typedef __attribute__((ext_vector_type(8))) short short8;
typedef __attribute__((ext_vector_type(4))) float f32x4;

__device__ __forceinline__ ushort f2b(float f) {   // f32 -> bf16 RNE
    unsigned u = __float_as_uint(f);
    u += 0x7fffu + ((u >> 16) & 1u);
    return (ushort)(u >> 16);
}

// ===================== ws layout (bytes) =====================
// A4: [256][256] @ 172032 | A5: [128][160] @ 303104
// WvRe/WvIm @ 344064/1941504 (2x 1597440)
// XsRe/XsIm @ 12058624/16318464 (2x 4259840) | Zre/Zim @ 20578304/24838144

// ---------------- graft item: Wv planes + A4 + A5 (idx in [86016, 970752)) -------------
__device__ __forceinline__ void pre_item_tail(int idx, const float* __restrict__ w,
                                              ushort* __restrict__ A4,
                                              ushort* __restrict__ A5,
                                              ushort* __restrict__ WvRe,
                                              ushort* __restrict__ WvIm) {
    if (idx < 151552) {                      // A4[m][k2]: inv col DFT, /128
        int j = idx - 86016;
        int m = j >> 8, k2 = j & 255;
        int part = m >> 7, h = m & 127;
        int kp = k2 >> 7, u = k2 & 127;
        float s, c;
        __sincosf(2.f * PI_F * (float)((u * h) & 127) / 128.f, &s, &c);
        float val = part == 0 ? (kp == 0 ? c : -s) : (kp == 0 ? s : c);
        A4[j] = f2b(val * (1.f / 128.f));
    } else if (idx < 172032) {               // A5[x][k2]: c2r, /128
        int j = idx - 151552;
        int x = j / 160, k2 = j - x * 160;
        int part = k2 / 80, v = k2 - part * 80;
        float s, c;
        __sincosf(2.f * PI_F * (float)((v * x) & 127) / 128.f, &s, &c);
        float cv = (v == 0 || v == 64) ? 1.f : 2.f;
        float val = (v < 65) ? (part == 0 ? cv * c : -cv * s) * (1.f / 128.f) : 0.f;
        A5[j] = f2b(val);
    } else {                                 // Wv[p][v][o][i]
        int xw = idx - 172032;               // 0..798719
        int i = xw & 63;
        int o = (xw >> 6) & 63;
        int pv = xw >> 12;
        int p = pv / WF;
        int v = pv % WF;
        const float* wp = w + ((size_t)o * 64 + i) * 9 + p * 3;
        float re = wp[0], im = 0.f;
#pragma unroll
        for (int q = 1; q <= 2; ++q) {
            int k = (v * q) & 127;
            float s, c;
            __sincosf(-2.f * PI_F * (float)k / 128.f, &s, &c);
            re += wp[q] * c;
            im += wp[q] * s;
        }
        WvRe[xw] = f2b(re);
        WvIm[xw] = f2b(im);
    }
}

// ---------------- k_fwd: self-sufficient; no x-staging; S2 via twiddle table ----------
// grid 256, 1024 threads (16 waves). LDS: A1L[160][136] 42.5 KB + B2[80][280] 44.8 KB
// + TW[128] 1 KB = 88.3 KiB.
#define B2P 280
#define A1P 136
__global__ __launch_bounds__(1024) void k_fwd(const float* __restrict__ x,
                                              const float* __restrict__ w,
                                              ushort* __restrict__ XsRe,
                                              ushort* __restrict__ XsIm,
                                              ushort* __restrict__ WvRe,
                                              ushort* __restrict__ WvIm,
                                              ushort* __restrict__ A4,
                                              ushort* __restrict__ A5) {
    __shared__ ushort A1L[160 * A1P];        // 42.5 KB
    __shared__ ushort B2[80 * B2P];          // 44.8 KB
    __shared__ __align__(16) float2 TW[128]; // e^{+2pi i k/128}
    int t = threadIdx.x;
    int img = blockIdx.x;
    const float* gx = x + (size_t)img * 16384;

    // ---- phase 0: A1L gen || TW gen || graft (no x staging) ----
    if (t < 128) {
        float s, c;
        __sincosf(2.f * PI_F * (float)t / 128.f, &s, &c);
        TW[t] = make_float2(c, s);
    }
    for (int idx = t; idx < 20480; idx += 1024) {
        int m = idx >> 7, k = idx & 127;
        int part = m / 80, v = m - part * 80;
        float s, c;
        __sincosf(2.f * PI_F * (float)((v * k) & 127) / 128.f, &s, &c);
        float val = (v < 65) ? (part ? -s : c) : 0.f;
        A1L[m * A1P + k] = f2b(val);
    }
    {
        int gtid = img * 1024 + t;           // [0, 262144)
        for (int idx = 86016 + gtid; idx < 970752; idx += 262144)
            pre_item_tail(idx, w, A4, A5, WvRe, WvIm);
    }
    __syncthreads();

    int lane = t & 63, wave = t >> 6;        // wave 0..15
    int lrow = lane & 15, lq = lane >> 4;

    // ---- S1: C[m=(part,v)][n=h]; wave (g=w>>3, nt=w&7); B-frag direct from global x ----
    {
        int g = wave >> 3, nt = wave & 7;
        int hrow = nt * 16 + lrow;
        f32x4 acc[5];
#pragma unroll
        for (int j = 0; j < 5; ++j) acc[j] = (f32x4){0.f, 0.f, 0.f, 0.f};
#pragma unroll
        for (int ks = 0; ks < 4; ++ks) {
            const float* xp = gx + hrow * 128 + ks * 32 + lq * 8;
            float4 f0 = *(const float4*)xp;
            float4 f1 = *(const float4*)(xp + 4);
            short8 b;
            b[0] = (short)f2b(f0.x); b[1] = (short)f2b(f0.y);
            b[2] = (short)f2b(f0.z); b[3] = (short)f2b(f0.w);
            b[4] = (short)f2b(f1.x); b[5] = (short)f2b(f1.y);
            b[6] = (short)f2b(f1.z); b[7] = (short)f2b(f1.w);
#pragma unroll
            for (int j = 0; j < 5; ++j) {
                int mt = g * 5 + j;
                short8 a = *(const short8*)&A1L[(mt * 16 + lrow) * A1P + ks * 32 + lq * 8];
                acc[j] = __builtin_amdgcn_mfma_f32_16x16x32_bf16(a, b, acc[j], 0, 0, 0);
            }
        }
#pragma unroll
        for (int j = 0; j < 5; ++j) {
            int m0 = (g * 5 + j) * 16 + lq * 4;
            int part = m0 >= 80;
            int v0 = m0 - part * 80;
#pragma unroll
            for (int e = 0; e < 4; ++e)
                B2[(v0 + e) * B2P + part * 128 + hrow] = f2b(acc[j][e]);
        }
    }
    __syncthreads();

    // ---- S2 (swapped): C[m=v][n=(part,u)]; wave owns n-tile = wave; B-frags from TW ----
    {
        int nt = wave;
        int part = nt >= 8;
        int um = (nt & 7) * 16 + lrow;       // u_m of the A2 row this lane supplies
        f32x4 acc[5];
#pragma unroll
        for (int mt = 0; mt < 5; ++mt) acc[mt] = (f32x4){0.f, 0.f, 0.f, 0.f};
#pragma unroll
        for (int ks = 0; ks < 8; ++ks) {
            int kp = ks >> 2;
            int hbase = (ks & 3) * 32 + lq * 8;
            short8 bfr;
            int idx = (um * hbase) & 127;
#pragma unroll
            for (int e = 0; e < 8; ++e) {
                float2 tw = TW[idx];
                // A2 value: part0: (kp==0? c : s); part1: (kp==0? -s : c)
                float val = !part ? (kp == 0 ? tw.x : tw.y)
                                  : (kp == 0 ? -tw.y : tw.x);
                bfr[e] = (short)f2b(val);
                idx = (idx + um) & 127;
            }
#pragma unroll
            for (int mt = 0; mt < 5; ++mt) {
                short8 a = *(short8*)&B2[(mt * 16 + lrow) * B2P + ks * 32 + lq * 8];
                acc[mt] = __builtin_amdgcn_mfma_f32_16x16x32_bf16(a, bfr, acc[mt], 0, 0, 0);
            }
        }
        int u = (nt & 7) * 16 + lrow;
        int u_out = (u + 64) & 127;
        int du = u_out - 64;
        ushort* dimg = (part ? XsIm : XsRe) + (size_t)img * CPLX_PER_IMG;
#pragma unroll
        for (int mt = 0; mt < 5; ++mt)
#pragma unroll
            for (int e = 0; e < 4; ++e) {
                int v_in = mt * 16 + lq * 4 + e;
                if (v_in < 65) {
                    int v_out = v_in + 32; if (v_out >= 65) v_out -= 65;
                    int dv = v_out - 64;
                    bool keep = (du * du + dv * dv) > 900;
                    dimg[v_out * 128 + u_out] = keep ? f2b(acc[mt][e]) : (ushort)0;
                }
            }
    }
}

// ---------------- k_gemm: per-(v,b) complex GEMM via bf16 MFMA + phase fold (R14 exact) --
#define AP 72
__global__ __launch_bounds__(256, 2) void k_gemm(const ushort* __restrict__ XsRe,
                                                 const ushort* __restrict__ XsIm,
                                                 const ushort* __restrict__ WvRe,
                                                 const ushort* __restrict__ WvIm,
                                                 ushort* __restrict__ Zre,
                                                 ushort* __restrict__ Zim) {
    __shared__ ushort XTre[128 * AP], XTim[128 * AP];
    __shared__ ushort WSre[64 * AP],  WSim[64 * AP];
    int t = threadIdx.x;
    int v = blockIdx.x >> 2;
    int b = blockIdx.x & 3;
    {
        int u = t & 127, qh = t >> 7;
#pragma unroll
        for (int q8 = 0; q8 < 8; ++q8) {
            int q = qh * 8 + q8;
            ushort re4[4], im4[4];
#pragma unroll
            for (int c = 0; c < 4; ++c) {
                int i = q * 4 + c;
                size_t off = ((size_t)(b * 64 + i) * WF + v) * 128 + u;
                re4[c] = XsRe[off];
                im4[c] = XsIm[off];
            }
            *(ushort4*)&XTre[u * AP + q * 4] = make_ushort4(re4[0], re4[1], re4[2], re4[3]);
            *(ushort4*)&XTim[u * AP + q * 4] = make_ushort4(im4[0], im4[1], im4[2], im4[3]);
        }
    }
    int lane = t & 63, wave = t >> 6;
    int lrow = lane & 15, lq = lane >> 4;
    int u0 = wave * 32;
    f32x4 fRe[8], fIm[8];
#pragma unroll
    for (int m = 0; m < 8; ++m) {
        fRe[m] = (f32x4){0.f, 0.f, 0.f, 0.f};
        fIm[m] = (f32x4){0.f, 0.f, 0.f, 0.f};
    }
    for (int p = 0; p < 3; ++p) {
        if (p) __syncthreads();
        {
            const ushort* gr = WvRe + ((size_t)(p * WF + v)) * 4096;
            const ushort* gi = WvIm + ((size_t)(p * WF + v)) * 4096;
#pragma unroll
            for (int cc = 0; cc < 2; ++cc) {
                int c = t + cc * 256;
                int o = c >> 3, i0 = (c & 7) * 8;
                *(short8*)&WSre[o * AP + i0] = *(const short8*)&gr[c * 8];
                *(short8*)&WSim[o * AP + i0] = *(const short8*)&gi[c * 8];
            }
        }
        __syncthreads();
        f32x4 pRe[8], pIm[8];
#pragma unroll
        for (int m = 0; m < 8; ++m) {
            pRe[m] = (f32x4){0.f, 0.f, 0.f, 0.f};
            pIm[m] = (f32x4){0.f, 0.f, 0.f, 0.f};
        }
#pragma unroll
        for (int ks = 0; ks < 2; ++ks) {
            int kb = ks * 32 + lq * 8;
            short8 br[2], bi[2], bin[2];
#pragma unroll
            for (int ut = 0; ut < 2; ++ut) {
                int u = u0 + ut * 16 + lrow;
                br[ut] = *(const short8*)&XTre[u * AP + kb];
                bi[ut] = *(const short8*)&XTim[u * AP + kb];
                bin[ut] = bi[ut] ^ (short)0x8000;
            }
#pragma unroll
            for (int ot = 0; ot < 4; ++ot) {
                int o = ot * 16 + lrow;
                short8 ar = *(const short8*)&WSre[o * AP + kb];
                short8 ai = *(const short8*)&WSim[o * AP + kb];
#pragma unroll
                for (int ut = 0; ut < 2; ++ut) {
                    int m = ot * 2 + ut;
                    pRe[m] = __builtin_amdgcn_mfma_f32_16x16x32_bf16(ai, bin[ut], pRe[m], 0, 0, 0);
                    pRe[m] = __builtin_amdgcn_mfma_f32_16x16x32_bf16(ar, br[ut],  pRe[m], 0, 0, 0);
                    pIm[m] = __builtin_amdgcn_mfma_f32_16x16x32_bf16(ai, br[ut],  pIm[m], 0, 0, 0);
                    pIm[m] = __builtin_amdgcn_mfma_f32_16x16x32_bf16(ar, bi[ut],  pIm[m], 0, 0, 0);
                }
            }
        }
#pragma unroll
        for (int ut = 0; ut < 2; ++ut) {
            int u = u0 + ut * 16 + lrow;
            float sn, cn;
            __sincosf(-2.f * PI_F * (float)(u * p) / 128.f, &sn, &cn);
#pragma unroll
            for (int ot = 0; ot < 4; ++ot) {
                int m = ot * 2 + ut;
#pragma unroll
                for (int e = 0; e < 4; ++e) {
                    fRe[m][e] += pRe[m][e] * cn - pIm[m][e] * sn;
                    fIm[m][e] += pIm[m][e] * cn + pRe[m][e] * sn;
                }
            }
        }
    }
#pragma unroll
    for (int ot = 0; ot < 4; ++ot)
#pragma unroll
        for (int ut = 0; ut < 2; ++ut) {
            int m = ot * 2 + ut;
            int u = u0 + ut * 16 + lrow;
#pragma unroll
            for (int e = 0; e < 4; ++e) {
                int o = ot * 16 + lq * 4 + e;
                size_t idx = ((size_t)(b * 64 + o) * WF + v) * 128 + u;
                Zre[idx] = f2b(fRe[m][e]);
                Zim[idx] = f2b(fIm[m][e]);
            }
        }
}

// ---------------- k_inv: per-ch S4 + S5 (R14 exact) ----------------
#define B3P 168
__global__ __launch_bounds__(1024) void k_inv(const ushort* __restrict__ Zre,
                                              const ushort* __restrict__ Zim,
                                              const ushort* __restrict__ A4,
                                              const ushort* __restrict__ A5,
                                              const float* __restrict__ bias,
                                              float* __restrict__ out) {
    __shared__ ushort B1[80 * B2P];          // 44.8 KB
    __shared__ ushort B2[128 * B3P];         // 43.0 KB
    int t = threadIdx.x;
    int ch = blockIdx.x;
    for (int c = t; c < 2080; c += 1024) {   // stage Z -> [v][kp*128+u]
        int r = c >> 5, sl = c & 31;
        const ushort* src = (sl < 16 ? Zre : Zim) + ((size_t)ch * WF + r) * 128 + (sl & 15) * 8;
        *(short8*)&B1[r * B2P + sl * 8] = *(const short8*)src;
    }
    if (t < 480) {                           // zero pad rows v=65..79
        int r = 65 + (t >> 5), sl = t & 31;
        short8 z = {0, 0, 0, 0, 0, 0, 0, 0};
        *(short8*)&B1[r * B2P + sl * 8] = z;
    }
    __syncthreads();
    int lane = t & 63, wave = t >> 6;        // wave 0..15
    int lrow = lane & 15, lq = lane >> 4;

    // ---- S4: C[m=(part,h)][n=v]; wave owns m-tile = wave, all 5 n-tiles ----
    {
        int mt = wave;
        f32x4 acc[5];
#pragma unroll
        for (int nt = 0; nt < 5; ++nt) acc[nt] = (f32x4){0.f, 0.f, 0.f, 0.f};
#pragma unroll
        for (int ks = 0; ks < 8; ++ks) {
            short8 a = *(const short8*)&A4[(mt * 16 + lrow) * 256 + ks * 32 + lq * 8];
#pragma unroll
            for (int nt = 0; nt < 5; ++nt) {
                short8 b = *(short8*)&B1[(nt * 16 + lrow) * B2P + ks * 32 + lq * 8];
                acc[nt] = __builtin_amdgcn_mfma_f32_16x16x32_bf16(a, b, acc[nt], 0, 0, 0);
            }
        }
        int part = mt >= 8;
        int h0 = mt * 16 + lq * 4 - part * 128;
#pragma unroll
        for (int nt = 0; nt < 5; ++nt) {
            int v = nt * 16 + lrow;
#pragma unroll
            for (int e = 0; e < 4; ++e)
                B2[(h0 + e) * B3P + part * 80 + v] = f2b(acc[nt][e]);
        }
    }
    __syncthreads();

    // ---- S5 (swapped): C[m=h][n=x]; wave (mt=w&7, nh=w>>3): 4 n-tiles ----
    {
        int mt = wave & 7, nh = wave >> 3;
        f32x4 acc[4];
#pragma unroll
        for (int jn = 0; jn < 4; ++jn) acc[jn] = (f32x4){0.f, 0.f, 0.f, 0.f};
#pragma unroll
        for (int ks = 0; ks < 5; ++ks) {
            short8 a = *(short8*)&B2[(mt * 16 + lrow) * B3P + ks * 32 + lq * 8];
#pragma unroll
            for (int jn = 0; jn < 4; ++jn) {
                int nt = nh * 4 + jn;
                short8 b = *(const short8*)&A5[(nt * 16 + lrow) * 160 + ks * 32 + lq * 8];
                acc[jn] = __builtin_amdgcn_mfma_f32_16x16x32_bf16(a, b, acc[jn], 0, 0, 0);
            }
        }
        float bo = bias[ch & 63];
        float* go = out + (size_t)ch * 16384;
#pragma unroll
        for (int jn = 0; jn < 4; ++jn) {
            int xx = (nh * 4 + jn) * 16 + lrow;
#pragma unroll
            for (int e = 0; e < 4; ++e) {
                int h = mt * 16 + lq * 4 + e;
                go[h * 128 + xx] = acc[jn][e] + bo;
            }
        }
    }
}

extern "C" void kernel_launch(void* const* d_in, const int* in_sizes, int n_in,
                              void* d_out, int out_size, void* d_ws, size_t ws_size,
                              hipStream_t stream) {
    const float* x = (const float*)d_in[0];      // [4,64,128,128]
    const float* w = (const float*)d_in[1];      // [64,64,3,3]
    const float* bias = (const float*)d_in[2];   // [64]
    float* out = (float*)d_out;                  // [4,64,128,128]

    char* ws = (char*)d_ws;
    ushort* A4   = (ushort*)(ws + 172032);
    ushort* A5   = (ushort*)(ws + 303104);
    ushort* WvRe = (ushort*)(ws + 344064);
    ushort* WvIm = (ushort*)(ws + 1941504);
    ushort* XsRe = (ushort*)(ws + 12058624);
    ushort* XsIm = (ushort*)(ws + 16318464);
    ushort* Zre  = (ushort*)(ws + 20578304);
    ushort* Zim  = (ushort*)(ws + 24838144);

    k_fwd<<<NB * NC, 1024, 0, stream>>>(x, w, XsRe, XsIm, WvRe, WvIm, A4, A5);
    k_gemm<<<WF * NB, 256, 0, stream>>>(XsRe, XsIm, WvRe, WvIm, Zre, Zim);
    k_inv<<<NB * NC, 1024, 0, stream>>>(Zre, Zim, A4, A5, bias, out);
}